// Round 1
// baseline (625.341 us; speedup 1.0000x reference)
//
#include <hip/hip_runtime.h>
#include <hip/hip_bf16.h>
#include <math.h>

// ---------------------------------------------------------------------------
// BitNet-b1.58 MLP: x -> bitlinear(W1,b1) -> gelu(erf) -> bitlinear(W2,b2)
// Exact-integer formulation: int8 x int8 -> int32 MFMA, dequant in epilogue.
// ---------------------------------------------------------------------------

typedef int int32x4 __attribute__((ext_vector_type(4)));

typedef const void __attribute__((address_space(1))) gv_t;
typedef void __attribute__((address_space(3))) lv_t;

__device__ inline void gload_lds16(const signed char* g, signed char* l) {
  __builtin_amdgcn_global_load_lds((gv_t*)g, (lv_t*)l, 16, 0, 0);
}

__device__ inline float gelu_erf(float v) {
  return 0.5f * v * (1.0f + erff(v * 0.70710678118654752440f));
}

__device__ inline void store_gt(float* p, float v) { *p = v; }
__device__ inline void store_gt(__hip_bfloat16* p, float v) {
  unsigned u = __float_as_uint(v);
  u += 0x7fffu + ((u >> 16) & 1u);          // RNE to bf16
  *(unsigned short*)p = (unsigned short)(u >> 16);
}

__device__ inline void load4v(const float* p, float v[4]) {
  const float4 t = *(const float4*)p;
  v[0] = t.x; v[1] = t.y; v[2] = t.z; v[3] = t.w;
}
__device__ inline void load4v(const __hip_bfloat16* p, float v[4]) {
  const ushort4 t = *(const ushort4*)p;
  v[0] = __uint_as_float((unsigned)t.x << 16);
  v[1] = __uint_as_float((unsigned)t.y << 16);
  v[2] = __uint_as_float((unsigned)t.z << 16);
  v[3] = __uint_as_float((unsigned)t.w << 16);
}

// --------------------------- w_scale reduction ------------------------------
// Deterministic two-stage f64 mean(|W|): block = 8192 contiguous floats.
__global__ __launch_bounds__(256) void absmean_partial(
    const float* __restrict__ W, double* __restrict__ part) {
  const int tid = threadIdx.x;
  const long base = (long)blockIdx.x * 8192;
  double s = 0.0;
#pragma unroll
  for (int c = 0; c < 8; ++c) {
    const float4 v = *(const float4*)&W[base + c * 1024 + tid * 4];
    s += (double)fabsf(v.x) + (double)fabsf(v.y) +
         (double)fabsf(v.z) + (double)fabsf(v.w);
  }
  __shared__ double sm[256];
  sm[tid] = s; __syncthreads();
  for (int off = 128; off; off >>= 1) {
    if (tid < off) sm[tid] += sm[tid + off];
    __syncthreads();
  }
  if (tid == 0) part[blockIdx.x] = sm[0];
}

__global__ __launch_bounds__(256) void absmean_final(
    const double* __restrict__ part, double* __restrict__ out, double n) {
  const int tid = threadIdx.x;
  __shared__ double sm[256];
  sm[tid] = part[tid] + part[tid + 256];
  __syncthreads();
  for (int off = 128; off; off >>= 1) {
    if (tid < off) sm[tid] += sm[tid + off];
    __syncthreads();
  }
  if (tid == 0) out[0] = fmax(sm[0] / n, 1e-5);
}

// --------------------------- weight ternarization ---------------------------
__global__ __launch_bounds__(256) void quant_w(
    const float* __restrict__ W, const double* __restrict__ wsP,
    signed char* __restrict__ Wq) {
  const double ws = *wsP;
  const long i = ((long)blockIdx.x * 256 + threadIdx.x) * 4;
  const float4 v = *(const float4*)&W[i];
  const float vv[4] = {v.x, v.y, v.z, v.w};
  int pack = 0;
#pragma unroll
  for (int q = 0; q < 4; ++q) {
    double r = rint((double)vv[q] / ws);   // RNE, matches jnp.round
    r = fmin(fmax(r, -1.0), 1.0);
    pack |= (((int)r) & 0xff) << (8 * q);
  }
  *(int*)&Wq[i] = pack;
}

// --------------------------- per-token activation quant ---------------------
template <int L, typename GT>
__global__ __launch_bounds__(256) void quant_rows(
    const GT* __restrict__ X, signed char* __restrict__ Xq,
    float* __restrict__ dsc) {
  constexpr int CH = L / 1024;
  const long row = blockIdx.x;
  const int tid = threadIdx.x;
  const GT* xr = X + row * (long)L;
  float v[CH][4];
  float m = 0.f;
#pragma unroll
  for (int c = 0; c < CH; ++c) {
    load4v(xr + c * 1024 + tid * 4, v[c]);
#pragma unroll
    for (int q = 0; q < 4; ++q) m = fmaxf(m, fabsf(v[c][q]));
  }
#pragma unroll
  for (int off = 32; off; off >>= 1) m = fmaxf(m, __shfl_down(m, off, 64));
  __shared__ float wmx[4];
  if ((tid & 63) == 0) wmx[tid >> 6] = m;
  __syncthreads();
  float ms = fmaxf(fmaxf(wmx[0], wmx[1]), fmaxf(wmx[2], wmx[3]));
  ms = fmaxf(ms, 1e-5f);
  const double inv = 127.0 / (double)ms;
#pragma unroll
  for (int c = 0; c < CH; ++c) {
    int pack = 0;
#pragma unroll
    for (int q = 0; q < 4; ++q) {
      double r = rint((double)v[c][q] * inv);
      r = fmin(fmax(r, -128.0), 127.0);
      pack |= (((int)r) & 0xff) << (8 * q);
    }
    *(int*)&Xq[row * (long)L + c * 1024 + tid * 4] = pack;
  }
  if (tid == 0) dsc[row] = (float)((double)ms / 127.0);
}

// --------------------------- int8 GEMM (A[M][K] * B[N][K]^T) -----------------
// 128x128 tile, BK=64, 4 waves (2x2), mfma_i32_16x16x64_i8, global_load_lds.
template <bool GELU, typename GT>
__global__ __launch_bounds__(256) void gemm_i8_128(
    const signed char* __restrict__ A, const signed char* __restrict__ Bm,
    const float* __restrict__ dA, const double* __restrict__ wsB,
    const float* __restrict__ bias, GT* __restrict__ C, int K, int Ncol) {
  __shared__ signed char As[8192];
  __shared__ signed char Bs[8192];
  const int tid = threadIdx.x;
  const int lane = tid & 63;
  const int wave = tid >> 6;
  const int wm = wave >> 1;
  const int wn = wave & 1;
  const long rowBase = (long)blockIdx.y * 128;
  const long colBase = (long)blockIdx.x * 128;

  // Staging: thread t loads 16B; LDS linear (row-major [128][64] i8).
  const int idx0 = tid << 4;          // 0..4080
  const int r0 = idx0 >> 6;           // 0..63
  const int c0 = idx0 & 63;
  const signed char* gA0 = A + (rowBase + r0) * (long)K + c0;
  const signed char* gA1 = gA0 + 64L * K;
  const signed char* gB0 = Bm + (colBase + r0) * (long)K + c0;
  const signed char* gB1 = gB0 + 64L * K;

  int32x4 acc[4][4] = {};
  const int kc = (lane >> 4) << 4;    // k-chunk within BK=64
  const int rl = lane & 15;

  for (int k0 = 0; k0 < K; k0 += 64) {
    gload_lds16(gA0, &As[idx0]);
    gload_lds16(gA1, &As[4096 + idx0]);
    gload_lds16(gB0, &Bs[idx0]);
    gload_lds16(gB1, &Bs[4096 + idx0]);
    gA0 += 64; gA1 += 64; gB0 += 64; gB1 += 64;
    __syncthreads();
    int32x4 af[4], bf[4];
#pragma unroll
    for (int i = 0; i < 4; ++i)
      af[i] = *(const int32x4*)&As[(wm * 64 + i * 16 + rl) * 64 + kc];
#pragma unroll
    for (int i = 0; i < 4; ++i)
      bf[i] = *(const int32x4*)&Bs[(wn * 64 + i * 16 + rl) * 64 + kc];
#pragma unroll
    for (int i = 0; i < 4; ++i)
#pragma unroll
      for (int j = 0; j < 4; ++j)
        acc[i][j] =
            __builtin_amdgcn_mfma_i32_16x16x64_i8(af[i], bf[j], acc[i][j], 0, 0, 0);
    __syncthreads();
  }

  // Epilogue: C/D layout col=lane&15, row=(lane>>4)*4+reg  [guide §3].
  const double wsd = *wsB;
  const int rquad = (lane >> 4) * 4;
#pragma unroll
  for (int i = 0; i < 4; ++i) {
#pragma unroll
    for (int r = 0; r < 4; ++r) {
      const long row = rowBase + wm * 64 + i * 16 + rquad + r;
      const float sc = (float)((double)dA[row] * wsd);
#pragma unroll
      for (int j = 0; j < 4; ++j) {
        const long col = colBase + wn * 64 + j * 16 + rl;
        float v = (float)acc[i][j][r] * sc + bias[col];
        if (GELU) v = gelu_erf(v);
        store_gt(&C[row * (long)Ncol + col], v);
      }
    }
  }
}

// ---------------------------------------------------------------------------
extern "C" void kernel_launch(void* const* d_in, const int* in_sizes, int n_in,
                              void* d_out, int out_size, void* d_ws,
                              size_t ws_size, hipStream_t stream) {
  const float* x  = (const float*)d_in[0];
  const float* W1 = (const float*)d_in[1];
  const float* b1 = (const float*)d_in[2];
  const float* W2 = (const float*)d_in[3];
  const float* b2 = (const float*)d_in[4];
  const int D = in_sizes[4];                 // 1024
  const int H = in_sizes[2];                 // 4096
  const long M = (long)in_sizes[0] / D;      // 32768
  float* out = (float*)d_out;

  if (D != 1024 || H != 4096 || (M % 128) != 0) return;  // shape contract

  char* wsp = (char*)d_ws;
  size_t off = 0;
  auto alloc = [&](size_t bytes) {
    void* p = wsp + off;
    off = (off + bytes + 255) & ~(size_t)255;
    return p;
  };
  signed char* wq1 = (signed char*)alloc((size_t)H * D);
  signed char* wq2 = (signed char*)alloc((size_t)D * H);
  signed char* xq  = (signed char*)alloc((size_t)M * D);
  signed char* gq  = (signed char*)alloc((size_t)M * H);
  float* dx = (float*)alloc((size_t)M * 4);
  float* dg = (float*)alloc((size_t)M * 4);
  double* part = (double*)alloc(512 * 8);
  double* ws1 = (double*)alloc(8);
  double* ws2 = (double*)alloc(8);
  const size_t g_f32_bytes = (size_t)M * H * 4;
  const bool g32 = (off + g_f32_bytes) <= ws_size;
  const size_t g_bytes = g32 ? g_f32_bytes : (size_t)M * H * 2;
  if (off + g_bytes > ws_size) return;  // cannot run
  void* g = alloc(g_bytes);

  const long nW = (long)H * D;  // 4194304 for both W1 and W2
  absmean_partial<<<nW / 8192, 256, 0, stream>>>(W1, part);
  absmean_final<<<1, 256, 0, stream>>>(part, ws1, (double)nW);
  absmean_partial<<<nW / 8192, 256, 0, stream>>>(W2, part);
  absmean_final<<<1, 256, 0, stream>>>(part, ws2, (double)nW);
  quant_w<<<nW / 1024, 256, 0, stream>>>(W1, ws1, wq1);
  quant_w<<<nW / 1024, 256, 0, stream>>>(W2, ws2, wq2);
  quant_rows<1024, float><<<M, 256, 0, stream>>>(x, xq, dx);

  dim3 g1(H / 128, M / 128);
  dim3 g2(D / 128, M / 128);
  if (g32) {
    gemm_i8_128<true, float><<<g1, 256, 0, stream>>>(
        xq, wq1, dx, ws1, b1, (float*)g, D, H);
    quant_rows<4096, float><<<M, 256, 0, stream>>>((const float*)g, gq, dg);
  } else {
    gemm_i8_128<true, __hip_bfloat16><<<g1, 256, 0, stream>>>(
        xq, wq1, dx, ws1, b1, (__hip_bfloat16*)g, D, H);
    quant_rows<4096, __hip_bfloat16><<<M, 256, 0, stream>>>(
        (const __hip_bfloat16*)g, gq, dg);
  }
  gemm_i8_128<false, float><<<g2, 256, 0, stream>>>(
      gq, wq2, dg, ws2, b2, out, H, D);
}

// Round 2
// 477.370 us; speedup vs baseline: 1.3100x; 1.3100x over previous
//
#include <hip/hip_runtime.h>
#include <hip/hip_bf16.h>
#include <math.h>

// ---------------------------------------------------------------------------
// BitNet-b1.58 MLP: x -> bitlinear(W1,b1) -> gelu(erf) -> bitlinear(W2,b2)
// Exact-integer formulation: int8 x int8 -> int32 MFMA, dequant in epilogue.
// GEMM: 256x256 tile, BK=64, 8 waves, 4-deep LDS ring, counted vmcnt,
//       XOR-swizzled LDS, setprio, XCD-chunked block swizzle.
// ---------------------------------------------------------------------------

typedef int int32x4 __attribute__((ext_vector_type(4)));

typedef const void __attribute__((address_space(1))) gv_t;
typedef void __attribute__((address_space(3))) lv_t;

__device__ __forceinline__ void gload_lds16(const signed char* g,
                                            signed char* l) {
  __builtin_amdgcn_global_load_lds((gv_t*)g, (lv_t*)l, 16, 0, 0);
}

__device__ __forceinline__ float gelu_erf(float v) {
  return 0.5f * v * (1.0f + erff(v * 0.70710678118654752440f));
}

__device__ __forceinline__ void store_gt(float* p, float v) { *p = v; }
__device__ __forceinline__ void store_gt(__hip_bfloat16* p, float v) {
  unsigned u = __float_as_uint(v);
  u += 0x7fffu + ((u >> 16) & 1u);  // RNE to bf16
  *(unsigned short*)p = (unsigned short)(u >> 16);
}

__device__ __forceinline__ void load4v(const float* p, float v[4]) {
  const float4 t = *(const float4*)p;
  v[0] = t.x; v[1] = t.y; v[2] = t.z; v[3] = t.w;
}
__device__ __forceinline__ void load4v(const __hip_bfloat16* p, float v[4]) {
  const ushort4 t = *(const ushort4*)p;
  v[0] = __uint_as_float((unsigned)t.x << 16);
  v[1] = __uint_as_float((unsigned)t.y << 16);
  v[2] = __uint_as_float((unsigned)t.z << 16);
  v[3] = __uint_as_float((unsigned)t.w << 16);
}

// --------------------------- w_scale reduction ------------------------------
__global__ __launch_bounds__(256) void absmean_partial(
    const float* __restrict__ W, double* __restrict__ part) {
  const int tid = threadIdx.x;
  const long base = (long)blockIdx.x * 8192;
  double s = 0.0;
#pragma unroll
  for (int c = 0; c < 8; ++c) {
    const float4 v = *(const float4*)&W[base + c * 1024 + tid * 4];
    s += (double)fabsf(v.x) + (double)fabsf(v.y) +
         (double)fabsf(v.z) + (double)fabsf(v.w);
  }
  __shared__ double sm[256];
  sm[tid] = s; __syncthreads();
  for (int off = 128; off; off >>= 1) {
    if (tid < off) sm[tid] += sm[tid + off];
    __syncthreads();
  }
  if (tid == 0) part[blockIdx.x] = sm[0];
}

__global__ __launch_bounds__(256) void absmean_final(
    const double* __restrict__ part, double* __restrict__ out, double n) {
  const int tid = threadIdx.x;
  __shared__ double sm[256];
  sm[tid] = part[tid] + part[tid + 256];
  __syncthreads();
  for (int off = 128; off; off >>= 1) {
    if (tid < off) sm[tid] += sm[tid + off];
    __syncthreads();
  }
  if (tid == 0) out[0] = fmax(sm[0] / n, 1e-5);
}

// --------------------------- weight ternarization ---------------------------
__global__ __launch_bounds__(256) void quant_w(
    const float* __restrict__ W, const double* __restrict__ wsP,
    signed char* __restrict__ Wq) {
  const double ws = *wsP;
  const long i = ((long)blockIdx.x * 256 + threadIdx.x) * 4;
  const float4 v = *(const float4*)&W[i];
  const float vv[4] = {v.x, v.y, v.z, v.w};
  int pack = 0;
#pragma unroll
  for (int q = 0; q < 4; ++q) {
    double r = rint((double)vv[q] / ws);  // RNE, matches jnp.round
    r = fmin(fmax(r, -1.0), 1.0);
    pack |= (((int)r) & 0xff) << (8 * q);
  }
  *(int*)&Wq[i] = pack;
}

// --------------------------- per-token activation quant ---------------------
template <int L, bool GELU, typename GT>
__global__ __launch_bounds__(256) void quant_rows(
    const GT* __restrict__ X, signed char* __restrict__ Xq,
    float* __restrict__ dsc) {
  constexpr int CH = L / 1024;
  const long row = blockIdx.x;
  const int tid = threadIdx.x;
  const GT* xr = X + row * (long)L;
  float v[CH][4];
  float m = 0.f;
#pragma unroll
  for (int c = 0; c < CH; ++c) {
    load4v(xr + c * 1024 + tid * 4, v[c]);
#pragma unroll
    for (int q = 0; q < 4; ++q) {
      if (GELU) v[c][q] = gelu_erf(v[c][q]);
      m = fmaxf(m, fabsf(v[c][q]));
    }
  }
#pragma unroll
  for (int off = 32; off; off >>= 1) m = fmaxf(m, __shfl_down(m, off, 64));
  __shared__ float wmx[4];
  if ((tid & 63) == 0) wmx[tid >> 6] = m;
  __syncthreads();
  float ms = fmaxf(fmaxf(wmx[0], wmx[1]), fmaxf(wmx[2], wmx[3]));
  ms = fmaxf(ms, 1e-5f);
  const double inv = 127.0 / (double)ms;
#pragma unroll
  for (int c = 0; c < CH; ++c) {
    int pack = 0;
#pragma unroll
    for (int q = 0; q < 4; ++q) {
      double r = rint((double)v[c][q] * inv);
      r = fmin(fmax(r, -128.0), 127.0);
      pack |= (((int)r) & 0xff) << (8 * q);
    }
    *(int*)&Xq[row * (long)L + c * 1024 + tid * 4] = pack;
  }
  if (tid == 0) dsc[row] = (float)((double)ms / 127.0);
}

// --------------------------- int8 GEMM (A[M][K] * B[N][K]^T) -----------------
// 256x256 tile, BK=64, 8 waves (2M x 4N), per-wave 128x64 output.
// LDS: 4-tile ring, A at [0,64K), B at [64K,128K), 16KB per tile per matrix.
// Swizzle: byte ^= ((row>>1)&3)<<4 (involution); global source pre-swizzled.
template <typename GT>
__global__ __launch_bounds__(512, 2) void gemm_i8_256(
    const signed char* __restrict__ A, const signed char* __restrict__ Bm,
    const float* __restrict__ dA, const double* __restrict__ wsB,
    const float* __restrict__ bias, GT* __restrict__ C,
    int K, int Ncol, int nx) {
  __shared__ signed char LDS[131072];
  const int tid = threadIdx.x;
  const int lane = tid & 63;
  const int wave = tid >> 6;
  const int wm = wave >> 2;  // 0..1
  const int wn = wave & 3;   // 0..3

  // XCD-chunked block swizzle (gridDim.x % 8 == 0 for both GEMMs)
  const int cpx = gridDim.x >> 3;
  const int wg = ((int)blockIdx.x & 7) * cpx + ((int)blockIdx.x >> 3);
  const long rowBase = (long)(wg / nx) * 256;
  const long colBase = (long)(wg % nx) * 256;
  const int NT = K >> 6;

  // Staging: thread covers LDS bytes d0 and d0+8192 per matrix (16B each).
  // Inverse-swizzled global source so that swizzled ds_read sees logical data.
  const int d0 = tid << 4;
  const int r0 = d0 >> 6;                                  // 0..127
  const int c0 = (d0 & 63) ^ (((d0 >> 7) & 3) << 4);       // pre-swizzled col
  const signed char* gA0 = A + (rowBase + r0) * (long)K + c0;
  const signed char* gA1 = A + (rowBase + r0 + 128) * (long)K + c0;
  const signed char* gB0 = Bm + (colBase + r0) * (long)K + c0;
  const signed char* gB1 = Bm + (colBase + r0 + 128) * (long)K + c0;

  auto STAGE = [&](int tt) {
    const int bb = (tt & 3) << 14;  // ring slot * 16384
    const int k0 = tt << 6;
    gload_lds16(gA0 + k0, &LDS[bb + d0]);
    gload_lds16(gA1 + k0, &LDS[bb + d0 + 8192]);
    gload_lds16(gB0 + k0, &LDS[65536 + bb + d0]);
    gload_lds16(gB1 + k0, &LDS[65536 + bb + d0 + 8192]);
  };

  // Swizzled ds_read offsets (within one 16KB tile buffer).
  const int rl = lane & 15;
  const int kc = (lane >> 4) << 4;  // 16B k-chunk per lane group
  int aoff[8], boff[4];
#pragma unroll
  for (int mi = 0; mi < 8; ++mi) {
    const int a = (wm * 128 + mi * 16 + rl) * 64 + kc;
    aoff[mi] = a ^ (((a >> 7) & 3) << 4);
  }
#pragma unroll
  for (int nj = 0; nj < 4; ++nj) {
    const int a = (wn * 64 + nj * 16 + rl) * 64 + kc;
    boff[nj] = a ^ (((a >> 7) & 3) << 4);
  }

  int32x4 acc[8][4] = {};
  STAGE(0); STAGE(1); STAGE(2);

  for (int t = 0; t < NT; ++t) {
    // Counted vmcnt: tiles t+1..t+2 (and t+3 being issued) stay in flight.
    if (t < NT - 2)       asm volatile("s_waitcnt vmcnt(8)" ::: "memory");
    else if (t == NT - 2) asm volatile("s_waitcnt vmcnt(4)" ::: "memory");
    else                  asm volatile("s_waitcnt vmcnt(0)" ::: "memory");
    __builtin_amdgcn_s_barrier();
    if (t + 3 < NT) STAGE(t + 3);

    const signed char* As = &LDS[(t & 3) << 14];
    const signed char* Bs = &LDS[65536 + ((t & 3) << 14)];
    int32x4 af[8], bf[4];
#pragma unroll
    for (int nj = 0; nj < 4; ++nj) bf[nj] = *(const int32x4*)&Bs[boff[nj]];
#pragma unroll
    for (int mi = 0; mi < 8; ++mi) af[mi] = *(const int32x4*)&As[aoff[mi]];
    __builtin_amdgcn_s_setprio(1);
#pragma unroll
    for (int mi = 0; mi < 8; ++mi)
#pragma unroll
      for (int nj = 0; nj < 4; ++nj)
        acc[mi][nj] = __builtin_amdgcn_mfma_i32_16x16x64_i8(
            af[mi], bf[nj], acc[mi][nj], 0, 0, 0);
    __builtin_amdgcn_s_setprio(0);
  }

  // Epilogue: C/D layout col=lane&15, row=(lane>>4)*4+reg.
  const double wsd = *wsB;
  const int rq = (lane >> 4) << 2;
  float bv[4];
#pragma unroll
  for (int nj = 0; nj < 4; ++nj)
    bv[nj] = bias[colBase + wn * 64 + nj * 16 + rl];
#pragma unroll
  for (int mi = 0; mi < 8; ++mi) {
#pragma unroll
    for (int r = 0; r < 4; ++r) {
      const long row = rowBase + wm * 128 + mi * 16 + rq + r;
      const float sc = (float)((double)dA[row] * wsd);
      GT* crow = C + row * (long)Ncol + colBase + wn * 64 + rl;
#pragma unroll
      for (int nj = 0; nj < 4; ++nj)
        store_gt(&crow[nj * 16], (float)acc[mi][nj][r] * sc + bv[nj]);
    }
  }
}

// ---------------------------------------------------------------------------
extern "C" void kernel_launch(void* const* d_in, const int* in_sizes, int n_in,
                              void* d_out, int out_size, void* d_ws,
                              size_t ws_size, hipStream_t stream) {
  const float* x  = (const float*)d_in[0];
  const float* W1 = (const float*)d_in[1];
  const float* b1 = (const float*)d_in[2];
  const float* W2 = (const float*)d_in[3];
  const float* b2 = (const float*)d_in[4];
  const int D = in_sizes[4];             // 1024
  const int H = in_sizes[2];             // 4096
  const long M = (long)in_sizes[0] / D;  // 32768
  float* out = (float*)d_out;

  if (D != 1024 || H != 4096 || (M % 256) != 0) return;  // shape contract

  char* wsp = (char*)d_ws;
  size_t off = 0;
  auto alloc = [&](size_t bytes) {
    void* p = wsp + off;
    off = (off + bytes + 255) & ~(size_t)255;
    return p;
  };
  signed char* wq1 = (signed char*)alloc((size_t)H * D);
  signed char* wq2 = (signed char*)alloc((size_t)D * H);
  signed char* xq  = (signed char*)alloc((size_t)M * D);
  signed char* gq  = (signed char*)alloc((size_t)M * H);
  float* dx = (float*)alloc((size_t)M * 4);
  float* dg = (float*)alloc((size_t)M * 4);
  double* part = (double*)alloc(512 * 8);
  double* ws1 = (double*)alloc(8);
  double* ws2 = (double*)alloc(8);
  const size_t g_f32_bytes = (size_t)M * H * 4;
  const bool g32 = (off + g_f32_bytes) <= ws_size;
  const size_t g_bytes = g32 ? g_f32_bytes : (size_t)M * H * 2;
  if (off + g_bytes > ws_size) return;  // cannot run
  void* g = alloc(g_bytes);

  const long nW = (long)H * D;
  absmean_partial<<<nW / 8192, 256, 0, stream>>>(W1, part);
  absmean_final<<<1, 256, 0, stream>>>(part, ws1, (double)nW);
  absmean_partial<<<nW / 8192, 256, 0, stream>>>(W2, part);
  absmean_final<<<1, 256, 0, stream>>>(part, ws2, (double)nW);
  quant_w<<<nW / 1024, 256, 0, stream>>>(W1, ws1, wq1);
  quant_w<<<nW / 1024, 256, 0, stream>>>(W2, ws2, wq2);
  quant_rows<1024, false, float><<<M, 256, 0, stream>>>(x, xq, dx);

  const int g1 = (H / 256) * (int)(M / 256);  // 2048
  const int g2 = (D / 256) * (int)(M / 256);  // 512
  if (g32) {
    gemm_i8_256<float><<<g1, 512, 0, stream>>>(
        xq, wq1, dx, ws1, b1, (float*)g, D, H, H / 256);
    quant_rows<4096, true, float><<<M, 256, 0, stream>>>(
        (const float*)g, gq, dg);
  } else {
    gemm_i8_256<__hip_bfloat16><<<g1, 512, 0, stream>>>(
        xq, wq1, dx, ws1, b1, (__hip_bfloat16*)g, D, H, H / 256);
    quant_rows<4096, true, __hip_bfloat16><<<M, 256, 0, stream>>>(
        (const __hip_bfloat16*)g, gq, dg);
  }
  gemm_i8_256<float><<<g2, 512, 0, stream>>>(
      gq, wq2, dg, ws2, b2, out, H, D, D / 256);
}

// Round 3
// 462.268 us; speedup vs baseline: 1.3528x; 1.0327x over previous
//
#include <hip/hip_runtime.h>
#include <hip/hip_bf16.h>
#include <math.h>

// ---------------------------------------------------------------------------
// BitNet-b1.58 MLP: x -> bitlinear(W1,b1) -> gelu(erf) -> bitlinear(W2,b2)
// Exact-integer formulation: int8 x int8 -> int32 MFMA, dequant in epilogue.
// GEMM: m201-style 8-phase schedule. 256x256 tile, BK=128 (i8), 8 waves,
// 2-buffer LDS (128 KiB), counted vmcnt(4) once per K-tile, XOR swizzle
// ((row&7)<<4), setprio around MFMA clusters, XCD-chunked block swizzle.
// ---------------------------------------------------------------------------

typedef int int32x4 __attribute__((ext_vector_type(4)));

typedef const void __attribute__((address_space(1))) gv_t;
typedef void __attribute__((address_space(3))) lv_t;

__device__ __forceinline__ void gload_lds16(const signed char* g,
                                            signed char* l) {
  __builtin_amdgcn_global_load_lds((gv_t*)g, (lv_t*)l, 16, 0, 0);
}

__device__ __forceinline__ float gelu_erf(float v) {
  return 0.5f * v * (1.0f + erff(v * 0.70710678118654752440f));
}

__device__ __forceinline__ void store_gt(float* p, float v) { *p = v; }
__device__ __forceinline__ void store_gt(__hip_bfloat16* p, float v) {
  unsigned u = __float_as_uint(v);
  u += 0x7fffu + ((u >> 16) & 1u);  // RNE to bf16
  *(unsigned short*)p = (unsigned short)(u >> 16);
}

__device__ __forceinline__ void load4v(const float* p, float v[4]) {
  const float4 t = *(const float4*)p;
  v[0] = t.x; v[1] = t.y; v[2] = t.z; v[3] = t.w;
}
__device__ __forceinline__ void load4v(const __hip_bfloat16* p, float v[4]) {
  const ushort4 t = *(const ushort4*)p;
  v[0] = __uint_as_float((unsigned)t.x << 16);
  v[1] = __uint_as_float((unsigned)t.y << 16);
  v[2] = __uint_as_float((unsigned)t.z << 16);
  v[3] = __uint_as_float((unsigned)t.w << 16);
}

// --------------------------- w_scale reduction ------------------------------
__global__ __launch_bounds__(256) void absmean_partial(
    const float* __restrict__ W, double* __restrict__ part) {
  const int tid = threadIdx.x;
  const long base = (long)blockIdx.x * 8192;
  double s = 0.0;
#pragma unroll
  for (int c = 0; c < 8; ++c) {
    const float4 v = *(const float4*)&W[base + c * 1024 + tid * 4];
    s += (double)fabsf(v.x) + (double)fabsf(v.y) +
         (double)fabsf(v.z) + (double)fabsf(v.w);
  }
  __shared__ double sm[256];
  sm[tid] = s; __syncthreads();
  for (int off = 128; off; off >>= 1) {
    if (tid < off) sm[tid] += sm[tid + off];
    __syncthreads();
  }
  if (tid == 0) part[blockIdx.x] = sm[0];
}

__global__ __launch_bounds__(256) void absmean_final(
    const double* __restrict__ part, double* __restrict__ out, double n) {
  const int tid = threadIdx.x;
  __shared__ double sm[256];
  sm[tid] = part[tid] + part[tid + 256];
  __syncthreads();
  for (int off = 128; off; off >>= 1) {
    if (tid < off) sm[tid] += sm[tid + off];
    __syncthreads();
  }
  if (tid == 0) out[0] = fmax(sm[0] / n, 1e-5);
}

// --------------------------- weight ternarization ---------------------------
__global__ __launch_bounds__(256) void quant_w(
    const float* __restrict__ W, const double* __restrict__ wsP,
    signed char* __restrict__ Wq) {
  const double ws = *wsP;
  const long i = ((long)blockIdx.x * 256 + threadIdx.x) * 4;
  const float4 v = *(const float4*)&W[i];
  const float vv[4] = {v.x, v.y, v.z, v.w};
  int pack = 0;
#pragma unroll
  for (int q = 0; q < 4; ++q) {
    double r = rint((double)vv[q] / ws);  // RNE, matches jnp.round
    r = fmin(fmax(r, -1.0), 1.0);
    pack |= (((int)r) & 0xff) << (8 * q);
  }
  *(int*)&Wq[i] = pack;
}

// --------------------------- per-token activation quant ---------------------
template <int L, bool GELU, typename GT>
__global__ __launch_bounds__(256) void quant_rows(
    const GT* __restrict__ X, signed char* __restrict__ Xq,
    float* __restrict__ dsc) {
  constexpr int CH = L / 1024;
  const long row = blockIdx.x;
  const int tid = threadIdx.x;
  const GT* xr = X + row * (long)L;
  float v[CH][4];
  float m = 0.f;
#pragma unroll
  for (int c = 0; c < CH; ++c) {
    load4v(xr + c * 1024 + tid * 4, v[c]);
#pragma unroll
    for (int q = 0; q < 4; ++q) {
      if (GELU) v[c][q] = gelu_erf(v[c][q]);
      m = fmaxf(m, fabsf(v[c][q]));
    }
  }
#pragma unroll
  for (int off = 32; off; off >>= 1) m = fmaxf(m, __shfl_down(m, off, 64));
  __shared__ float wmx[4];
  if ((tid & 63) == 0) wmx[tid >> 6] = m;
  __syncthreads();
  float ms = fmaxf(fmaxf(wmx[0], wmx[1]), fmaxf(wmx[2], wmx[3]));
  ms = fmaxf(ms, 1e-5f);
  const double inv = 127.0 / (double)ms;
#pragma unroll
  for (int c = 0; c < CH; ++c) {
    int pack = 0;
#pragma unroll
    for (int q = 0; q < 4; ++q) {
      double r = rint((double)v[c][q] * inv);
      r = fmin(fmax(r, -128.0), 127.0);
      pack |= (((int)r) & 0xff) << (8 * q);
    }
    *(int*)&Xq[row * (long)L + c * 1024 + tid * 4] = pack;
  }
  if (tid == 0) dsc[row] = (float)((double)ms / 127.0);
}

// --------------------------- int8 GEMM, 8-phase -----------------------------
// C[M][N] = A[M][K] * Bm[N][K]^T, dequant+bias(+GELU via quant pass) epilogue.
// LDS map: A tiles [0,65536) (buf0/buf1 32KB each), B tiles [65536,131072).
// Tile = 256 rows x 128 B (i8). Swizzle: col ^= (row&7)<<4 (involution).
template <typename GT>
__global__ __launch_bounds__(512, 2) void gemm_i8_8ph(
    const signed char* __restrict__ A, const signed char* __restrict__ Bm,
    const float* __restrict__ dA, const double* __restrict__ wsB,
    const float* __restrict__ bias, GT* __restrict__ C,
    int K, int Ncol, int nx) {
  __shared__ signed char LDS[131072];
  const int tid = threadIdx.x;
  const int lane = tid & 63;
  const int wave = tid >> 6;
  const int wm = wave >> 2;  // 0..1
  const int wn = wave & 3;   // 0..3

  const int cpx = gridDim.x >> 3;
  const int wg = ((int)blockIdx.x & 7) * cpx + ((int)blockIdx.x >> 3);
  const long rowBase = (long)(wg / nx) * 256;
  const long colBase = (long)(wg % nx) * 256;
  const int NT = K >> 7;  // BK = 128

  // ---- staging: 4 x 16B per thread per matrix per K-tile ----
  const int dd = wave * 1024 + lane * 16;                // [0,8192)
  const int srow = dd >> 7;                              // 0..63
  const int scol = (dd & 127) ^ ((srow & 7) << 4);       // pre-swizzled src col
  const long k64 = 64L * K;
  const signed char* sA0 = A + (rowBase + srow) * (long)K + scol;
  const signed char* sB0 = Bm + (colBase + srow) * (long)K + scol;

  auto STAGE_A = [&](int t) {
    const signed char* p = sA0 + ((long)t << 7);
    signed char* l = &LDS[((t & 1) << 15) + dd];
#pragma unroll
    for (int i = 0; i < 4; ++i) gload_lds16(p + i * k64, l + i * 8192);
  };
  auto STAGE_B = [&](int t) {
    const signed char* p = sB0 + ((long)t << 7);
    signed char* l = &LDS[65536 + ((t & 1) << 15) + dd];
#pragma unroll
    for (int i = 0; i < 4; ++i) gload_lds16(p + i * k64, l + i * 8192);
  };

  // ---- ds_read fragment addressing ----
  const int rl = lane & 15;
  const int col0 = (((lane >> 4) << 4)) ^ ((rl & 7) << 4);  // swizzled kc0 col
  const int aRow = wm * 16384 + rl * 128;  // within A tile
  const int bRow = wn * 8192 + rl * 128;   // within B tile

  int32x4 acc[8][4] = {};

  // ---- prologue: B(0), A(0), B(1) staged; wait for tile 0 ----
  STAGE_B(0); STAGE_A(0); STAGE_B(1);
  asm volatile("s_waitcnt vmcnt(4)" ::: "memory");
  __builtin_amdgcn_s_barrier();

  for (int t = 0; t < NT; ++t) {
    const signed char* At = &LDS[(t & 1) << 15];
    const signed char* Bt = &LDS[65536 + ((t & 1) << 15)];
    int32x4 af[4], bf[4];

    auto LDA = [&](int mih, int kc6) {
#pragma unroll
      for (int i = 0; i < 4; ++i)
        af[i] = *(const int32x4*)(At + aRow + (mih * 4 + i) * 2048 +
                                  (col0 ^ kc6));
    };
    auto LDB = [&](int kc6) {
#pragma unroll
      for (int nj = 0; nj < 4; ++nj)
        bf[nj] = *(const int32x4*)(Bt + bRow + nj * 2048 + (col0 ^ kc6));
    };
    auto MFMA16 = [&](int mih) {
#pragma unroll
      for (int i = 0; i < 4; ++i)
#pragma unroll
        for (int nj = 0; nj < 4; ++nj)
          acc[mih * 4 + i][nj] = __builtin_amdgcn_mfma_i32_16x16x64_i8(
              af[i], bf[nj], acc[mih * 4 + i][nj], 0, 0, 0);
    };

    // ---- phase 0: rows wm*128+[0,64), kc0; issue A(t+1) ----
    LDB(0);
    LDA(0, 0);
    if (t + 1 < NT) STAGE_A(t + 1);
    __builtin_amdgcn_s_barrier();
    __builtin_amdgcn_s_setprio(1);
    MFMA16(0);
    __builtin_amdgcn_s_setprio(0);
    asm volatile("s_waitcnt lgkmcnt(0)" ::: "memory");
    __builtin_amdgcn_s_barrier();

    // ---- phase 1: rows +[64,128), kc0 ----
    LDA(1, 0);
    __builtin_amdgcn_s_barrier();
    __builtin_amdgcn_s_setprio(1);
    MFMA16(1);
    __builtin_amdgcn_s_setprio(0);
    asm volatile("s_waitcnt lgkmcnt(0)" ::: "memory");
    __builtin_amdgcn_s_barrier();

    // ---- phase 2: rows +[0,64), kc1 ----
    LDB(64);
    LDA(0, 64);
    __builtin_amdgcn_s_barrier();
    __builtin_amdgcn_s_setprio(1);
    MFMA16(0);
    __builtin_amdgcn_s_setprio(0);
    asm volatile("s_waitcnt lgkmcnt(0)" ::: "memory");
    __builtin_amdgcn_s_barrier();

    // ---- phase 3: rows +[64,128), kc1; issue B(t+2); counted vmcnt ----
    LDA(1, 64);
    if (t + 2 < NT) STAGE_B(t + 2);
    if (t < NT - 2) asm volatile("s_waitcnt vmcnt(4)" ::: "memory");
    else            asm volatile("s_waitcnt vmcnt(0)" ::: "memory");
    __builtin_amdgcn_s_barrier();
    __builtin_amdgcn_s_setprio(1);
    MFMA16(1);
    __builtin_amdgcn_s_setprio(0);
    asm volatile("s_waitcnt lgkmcnt(0)" ::: "memory");
    __builtin_amdgcn_s_barrier();
  }

  // ---- epilogue: C/D layout col=lane&15, row=(lane>>4)*4+reg ----
  const double wsd = *wsB;
  const int rq = (lane >> 4) << 2;
  float bv[4];
#pragma unroll
  for (int nj = 0; nj < 4; ++nj)
    bv[nj] = bias[colBase + wn * 64 + nj * 16 + rl];
#pragma unroll
  for (int mi = 0; mi < 8; ++mi) {
#pragma unroll
    for (int r = 0; r < 4; ++r) {
      const long row = rowBase + wm * 128 + mi * 16 + rq + r;
      const float sc = (float)((double)dA[row] * wsd);
      GT* crow = C + row * (long)Ncol + colBase + wn * 64 + rl;
#pragma unroll
      for (int nj = 0; nj < 4; ++nj)
        store_gt(&crow[nj * 16], (float)acc[mi][nj][r] * sc + bv[nj]);
    }
  }
}

// ---------------------------------------------------------------------------
extern "C" void kernel_launch(void* const* d_in, const int* in_sizes, int n_in,
                              void* d_out, int out_size, void* d_ws,
                              size_t ws_size, hipStream_t stream) {
  const float* x  = (const float*)d_in[0];
  const float* W1 = (const float*)d_in[1];
  const float* b1 = (const float*)d_in[2];
  const float* W2 = (const float*)d_in[3];
  const float* b2 = (const float*)d_in[4];
  const int D = in_sizes[4];             // 1024
  const int H = in_sizes[2];             // 4096
  const long M = (long)in_sizes[0] / D;  // 32768
  float* out = (float*)d_out;

  if (D != 1024 || H != 4096 || (M % 256) != 0) return;  // shape contract

  char* wsp = (char*)d_ws;
  size_t off = 0;
  auto alloc = [&](size_t bytes) {
    void* p = wsp + off;
    off = (off + bytes + 255) & ~(size_t)255;
    return p;
  };
  signed char* wq1 = (signed char*)alloc((size_t)H * D);
  signed char* wq2 = (signed char*)alloc((size_t)D * H);
  signed char* xq  = (signed char*)alloc((size_t)M * D);
  signed char* gq  = (signed char*)alloc((size_t)M * H);
  float* dx = (float*)alloc((size_t)M * 4);
  float* dg = (float*)alloc((size_t)M * 4);
  double* part = (double*)alloc(512 * 8);
  double* ws1 = (double*)alloc(8);
  double* ws2 = (double*)alloc(8);
  __hip_bfloat16* h = (__hip_bfloat16*)alloc((size_t)M * H * 2);
  if (off > ws_size) return;  // cannot run

  const long nW = (long)H * D;
  absmean_partial<<<nW / 8192, 256, 0, stream>>>(W1, part);
  absmean_final<<<1, 256, 0, stream>>>(part, ws1, (double)nW);
  absmean_partial<<<nW / 8192, 256, 0, stream>>>(W2, part);
  absmean_final<<<1, 256, 0, stream>>>(part, ws2, (double)nW);
  quant_w<<<nW / 1024, 256, 0, stream>>>(W1, ws1, wq1);
  quant_w<<<nW / 1024, 256, 0, stream>>>(W2, ws2, wq2);
  quant_rows<1024, false, float><<<M, 256, 0, stream>>>(x, xq, dx);

  const int g1 = (H / 256) * (int)(M / 256);  // 2048
  const int g2 = (D / 256) * (int)(M / 256);  // 512
  gemm_i8_8ph<__hip_bfloat16><<<g1, 512, 0, stream>>>(
      xq, wq1, dx, ws1, b1, h, D, H, H / 256);
  quant_rows<4096, true, __hip_bfloat16><<<M, 256, 0, stream>>>(h, gq, dg);
  gemm_i8_8ph<float><<<g2, 512, 0, stream>>>(
      gq, wq2, dg, ws2, b2, out, H, D, D / 256);
}